// Round 7
// baseline (161.982 us; speedup 1.0000x reference)
//
#include <hip/hip_runtime.h>
#include <hip/hip_fp16.h>
#include <stdint.h>

typedef __attribute__((ext_vector_type(4))) float f32x4;
typedef __attribute__((ext_vector_type(8))) short short8;

__device__ __forceinline__ unsigned short f2bf(float f) {
  unsigned int b = __float_as_uint(f);
  b = b + 0x7FFFu + ((b >> 16) & 1u);   // RNE
  return (unsigned short)(b >> 16);
}

#define CE(a, b) { float _lo = fminf((a), (b)), _hi = fmaxf((a), (b)); (a) = _lo; (b) = _hi; }

// Batcher odd-even merge of two ascending sorted 4-lists (x[0..3], x[4..7]) -> sorted 8
__device__ __forceinline__ void merge8(float x[8]) {
  CE(x[0], x[4]); CE(x[1], x[5]); CE(x[2], x[6]); CE(x[3], x[7]);
  CE(x[2], x[4]); CE(x[3], x[5]);
  CE(x[1], x[2]); CE(x[3], x[4]); CE(x[5], x[6]);
}

// ---------------------------------------------------------------------------
// Fused prep kernel: blocks 0..4095 = per-row NF4 quant+dequant of W -> qb,
//                    blocks 4096..8191 = x fp32 -> bf16 cvt
// ---------------------------------------------------------------------------
__global__ __launch_bounds__(256) void prep_kernel(const float* __restrict__ x,
                                                   const float* __restrict__ W,
                                                   const float* __restrict__ lut,
                                                   unsigned short* __restrict__ xb,
                                                   unsigned short* __restrict__ qb) {
  const int tid = threadIdx.x;

  if (blockIdx.x >= 4096) {
    // ---- cvt path ----
    int b = blockIdx.x - 4096;
    int base = b * 1024 + tid;   // float4 index
#pragma unroll
    for (int it = 0; it < 4; ++it) {
      int i = base + it * 256;
      f32x4 v = ((const f32x4*)x)[i];
      ushort4 u;
      u.x = f2bf(v[0]); u.y = f2bf(v[1]); u.z = f2bf(v[2]); u.w = f2bf(v[3]);
      ((ushort4*)xb)[i] = u;
    }
    return;
  }

  // ---- quant path ----
  const int C = 4096;
  const int row = blockIdx.x;
  const int lane = tid & 63;
  const int wv = tid >> 6;

  __shared__ float s_luth[16];   // fp16-rounded poles (dequant values)
  __shared__ float s_mid[15];    // decision midpoints on fp32 poles
  __shared__ float s_red[4][8];
  __shared__ float s_par[4];

  if (tid < 16) {
    float f = lut[tid];
    s_luth[tid] = __half2float(__float2half(f));  // .half() per reference
  }
  if (tid < 15) s_mid[tid] = 0.5f * (lut[tid] + lut[tid + 1]);

  const f32x4* Wp = (const f32x4*)(W + (size_t)row * C);
  f32x4 v[4];
#pragma unroll
  for (int i = 0; i < 4; ++i) v[i] = Wp[i * 256 + tid];

  // per-thread bottom-4 (ascending) and top-4 (ascending)
  float bot[4] = {__builtin_inff(), __builtin_inff(), __builtin_inff(), __builtin_inff()};
  float top[4] = {-__builtin_inff(), -__builtin_inff(), -__builtin_inff(), -__builtin_inff()};
#pragma unroll
  for (int i = 0; i < 4; ++i) {
#pragma unroll
    for (int j = 0; j < 4; ++j) {
      float f = v[i][j];
      bot[3] = fminf(bot[3], f); CE(bot[2], bot[3]); CE(bot[1], bot[2]); CE(bot[0], bot[1]);
      top[0] = fmaxf(top[0], f); CE(top[0], top[1]); CE(top[1], top[2]); CE(top[2], top[3]);
    }
  }

#pragma unroll
  for (int d = 1; d < 64; d <<= 1) {
    float xx[8];
#pragma unroll
    for (int j = 0; j < 4; ++j) { xx[j] = bot[j]; xx[4 + j] = __shfl_xor(bot[j], d); }
    merge8(xx);
#pragma unroll
    for (int j = 0; j < 4; ++j) bot[j] = xx[j];
#pragma unroll
    for (int j = 0; j < 4; ++j) { xx[j] = top[j]; xx[4 + j] = __shfl_xor(top[j], d); }
    merge8(xx);
#pragma unroll
    for (int j = 0; j < 4; ++j) top[j] = xx[4 + j];
  }

  if (lane == 0) {
#pragma unroll
    for (int j = 0; j < 4; ++j) { s_red[wv][j] = bot[j]; s_red[wv][4 + j] = top[j]; }
  }
  __syncthreads();

  if (tid == 0) {
    float a[8], b[8], m[8];
#pragma unroll
    for (int j = 0; j < 4; ++j) { a[j] = s_red[0][j]; a[4 + j] = s_red[1][j]; }
    merge8(a);
#pragma unroll
    for (int j = 0; j < 4; ++j) { b[j] = s_red[2][j]; b[4 + j] = s_red[3][j]; }
    merge8(b);
#pragma unroll
    for (int j = 0; j < 4; ++j) { m[j] = a[j]; m[4 + j] = b[j]; }
    merge8(m);
    float lower = m[2] + 0.0475f * (m[3] - m[2]);   // quantile 0.0005 -> idx 2.0475
#pragma unroll
    for (int j = 0; j < 4; ++j) { a[j] = s_red[0][4 + j]; a[4 + j] = s_red[1][4 + j]; }
    merge8(a);
#pragma unroll
    for (int j = 0; j < 4; ++j) { b[j] = s_red[2][4 + j]; b[4 + j] = s_red[3][4 + j]; }
    merge8(b);
#pragma unroll
    for (int j = 0; j < 4; ++j) { m[j] = a[4 + j]; m[4 + j] = b[4 + j]; }
    merge8(m);
    float upper = m[4] + 0.9525f * (m[5] - m[4]);   // quantile 0.9995 -> idx 4092.9525
    s_par[0] = lower; s_par[1] = upper;
  }
  __syncthreads();

  float lower = s_par[0], upper = s_par[1];

  float mn = __builtin_inff(), mx = -__builtin_inff();
#pragma unroll
  for (int i = 0; i < 4; ++i) {
#pragma unroll
    for (int j = 0; j < 4; ++j) {
      float f = v[i][j];
      bool outl = (f <= lower) || (f >= upper);
      if (!outl) { mn = fminf(mn, f); mx = fmaxf(mx, f); }
    }
  }
#pragma unroll
  for (int d = 1; d < 64; d <<= 1) {
    mn = fminf(mn, __shfl_xor(mn, d));
    mx = fmaxf(mx, __shfl_xor(mx, d));
  }
  if (lane == 0) { s_red[wv][0] = mn; s_red[wv][1] = mx; }
  __syncthreads();
  if (tid == 0) {
    float tmn = fminf(fminf(s_red[0][0], s_red[1][0]), fminf(s_red[2][0], s_red[3][0]));
    float tmx = fmaxf(fmaxf(s_red[0][1], s_red[1][1]), fmaxf(s_red[2][1], s_red[3][1]));
    s_par[2] = (tmx + tmn) * 0.5f;   // offset
    s_par[3] = (tmx - tmn) * 0.5f;   // rangeval
  }
  __syncthreads();
  float offset = s_par[2], range = s_par[3];
  float invr = 1.0f / range;

  unsigned short* outr = qb + (size_t)row * C;
#pragma unroll
  for (int i = 0; i < 4; ++i) {
    ushort4 o;
    unsigned short os[4];
#pragma unroll
    for (int j = 0; j < 4; ++j) {
      float f = v[i][j];
      bool outl = (f <= lower) || (f >= upper);
      float q;
      if (outl) {
        q = f;  // Q=0 pole -> weight passes through
      } else {
        // nearest pole via branchless binary search on midpoints.
        // strict '>' keeps the LOWER index on exact ties == argmin semantics.
        float ws = (f - offset) * invr;
        int bi = (ws > s_mid[7]) ? 8 : 0;
        bi += (ws > s_mid[bi + 3]) ? 4 : 0;
        bi += (ws > s_mid[bi + 1]) ? 2 : 0;
        bi += (ws > s_mid[bi]) ? 1 : 0;
        q = s_luth[bi] * range + offset;
      }
      if (!isfinite(q)) q = 0.0f;
      os[j] = f2bf(q);
    }
    o.x = os[0]; o.y = os[1]; o.z = os[2]; o.w = os[3];
    ((ushort4*)outr)[i * 256 + tid] = o;
  }
}

// ---------------------------------------------------------------------------
// GEMM: C = A * B^T (bf16 in, fp32 out). Round 7: K-tile-level pipeline.
// 256x256 tile, BK=64, 8 waves (2Mx4N), subtiled st_16x32 LDS (conflicts==0).
// 2 barriers per K-tile (was 8). Within a K-tile the kbuf is stable, so all
// intra-tile barriers removed; the compiler's own counted lgkmcnt(N) waits
// (G7) gate each MFMA quadrant on exactly the reads it needs:
//   [loop-carried: afL,bf0,bf1 reads issued at prev tile's tail]
//   q1 (lgkm(4) auto)  q2 (lgkm(0) auto)
//   issue afH reads    q3,q4 (lgkm(0) auto)   <- read service ∥ q1/q2 MFMA
//   BAR  (all kbuf-c reads drained by q3/q4 deps -> kbuf c free)
//   stage kbuf c <- t+2  (8 gload_lds)
//   VM8  (t+1's 8 landed; t+2's 8 in flight)   BAR  (t+1 visible to all)
//   issue next tile's 16 reads from kbuf c^1   <- service ∥ q3/q4 still in pipe
// ---------------------------------------------------------------------------
#define GK 4096

__device__ __forceinline__ void gload16(const void* gp, void* lp) {
  __builtin_amdgcn_global_load_lds(
      (const __attribute__((address_space(1))) unsigned int*)(uintptr_t)gp,
      (__attribute__((address_space(3))) unsigned int*)(unsigned int)(uintptr_t)lp,
      16, 0, 0);
}

#define BAR()    __builtin_amdgcn_s_barrier()
#define VM8()    asm volatile("s_waitcnt vmcnt(8)" ::: "memory")
#define PRIO1()  __builtin_amdgcn_s_setprio(1)
#define PRIO0()  __builtin_amdgcn_s_setprio(0)

__global__ __launch_bounds__(512, 2) void gemm_bt(const unsigned short* __restrict__ A,
                                                  const unsigned short* __restrict__ B,
                                                  float* __restrict__ C) {
  // [kbuf][rowhalf][16KB half-tile] ; total 128 KiB
  __shared__ __align__(16) unsigned short sA[2][2][8192];
  __shared__ __align__(16) unsigned short sB[2][2][8192];

  const int tid = threadIdx.x;
  const int lane = tid & 63;
  const int wv = tid >> 6;
  const int wm = wv >> 2, wn = wv & 3;       // 2 x 4 wave grid; wave tile 128 x 64
  const int fr = lane & 15, fk = lane >> 4;

  // XCD-aware swizzle: 256 blocks, 256 % 8 == 0 -> bijective
  int bi = blockIdx.x;
  int swz = (bi & 7) * 32 + (bi >> 3);
  int brow = swz >> 4, bcol = swz & 15;

  const unsigned short* Abase = A + (size_t)brow * 256 * GK;
  const unsigned short* Bbase = B + (size_t)bcol * 256 * GK;

  // read-side swizzled column byte within 64B row: fk*16 ^ (row-bit-3 << 5)
  const int cA = (fk * 16) ^ ((fr & 8) << 2);

  // stage source permutation (round 4, verified): LDS bytes [wv*1024+l*8192+lane*16)
  // hold global (row = l*64 + (wv>>1)*16 + (lane>>2),
  //              kbyte = (wv&1)*64 + ((lane&3)*16 ^ (lane&32 ? 32 : 0)))
  const int srow = (wv >> 1) * 16 + (lane >> 2);                 // + l*64
  const int skelt = ((wv & 1) * 64 + (((lane & 3) * 16) ^ ((lane & 32) ? 32 : 0))) >> 1;

  auto stage = [&](const unsigned short* gb, unsigned short* lb, int h, int kt) {
    const unsigned short* g = gb + ((size_t)h * 128) * GK + kt * 64 + skelt;
    char* lc = (char*)lb + wv * 1024 + lane * 16;
#pragma unroll
    for (int l = 0; l < 2; ++l)
      gload16(g + (size_t)(l * 64 + srow) * GK, lc + l * 8192);
  };

  f32x4 acc[8][4];
#pragma unroll
  for (int m = 0; m < 8; ++m)
#pragma unroll
    for (int n = 0; n < 4; ++n) acc[m][n] = (f32x4){0.f, 0.f, 0.f, 0.f};

  const int nsub = (wn & 1) * 4;       // B subtile-row base within rowhalf

  // ---- prologue: stage K-tiles 0 and 1 fully (16 loads); VM8 -> tile 0 landed
  stage(Abase, &sA[0][0][0], 0, 0);
  stage(Abase, &sA[0][1][0], 1, 0);
  stage(Bbase, &sB[0][0][0], 0, 0);
  stage(Bbase, &sB[0][1][0], 1, 0);
  stage(Abase, &sA[1][0][0], 0, 1);
  stage(Abase, &sA[1][1][0], 1, 1);
  stage(Bbase, &sB[1][0][0], 0, 1);
  stage(Bbase, &sB[1][1][0], 1, 1);
  VM8();
  BAR();

  short8 afL[4][2], afH[4][2], bf0[2][2], bf1[2][2];

  // pre-loop reads for tile 0 (afL, bf0, bf1)
  {
    const char* bA = (const char*)&sA[0][wm][0];
    const char* bB = (const char*)&sB[0][wn >> 1][0];
#pragma unroll
    for (int m = 0; m < 4; ++m)
#pragma unroll
      for (int kh = 0; kh < 2; ++kh)
        afL[m][kh] = *(const short8*)(bA + m * 2048 + kh * 1024 + fr * 64 + cA);
#pragma unroll
    for (int n = 0; n < 2; ++n)
#pragma unroll
      for (int kh = 0; kh < 2; ++kh) {
        bf0[n][kh] = *(const short8*)(bB + (nsub + n) * 2048 + kh * 1024 + fr * 64 + cA);
        bf1[n][kh] = *(const short8*)(bB + (nsub + n + 2) * 2048 + kh * 1024 + fr * 64 + cA);
      }
  }

#pragma unroll 1
  for (int t = 0; t < 64; ++t) {
    const int c = t & 1;
    const char* bA = (const char*)&sA[c][wm][0];
    const char* bAn = (const char*)&sA[c ^ 1][wm][0];
    const char* bBn = (const char*)&sB[c ^ 1][wn >> 1][0];

    // q1: (afL, bf0) ; q2: (afL, bf1)   [compiler emits counted lgkm waits]
    PRIO1();
#pragma unroll
    for (int m = 0; m < 4; ++m)
#pragma unroll
      for (int n = 0; n < 2; ++n)
#pragma unroll
        for (int kh = 0; kh < 2; ++kh)
          acc[m][n] = __builtin_amdgcn_mfma_f32_16x16x32_bf16(afL[m][kh], bf0[n][kh], acc[m][n], 0, 0, 0);
#pragma unroll
    for (int m = 0; m < 4; ++m)
#pragma unroll
      for (int n = 0; n < 2; ++n)
#pragma unroll
        for (int kh = 0; kh < 2; ++kh)
          acc[m][n + 2] = __builtin_amdgcn_mfma_f32_16x16x32_bf16(afL[m][kh], bf1[n][kh], acc[m][n + 2], 0, 0, 0);
    PRIO0();

    // afH reads (service overlaps q1/q2 MFMA in the pipe)
#pragma unroll
    for (int m = 0; m < 4; ++m)
#pragma unroll
      for (int kh = 0; kh < 2; ++kh)
        afH[m][kh] = *(const short8*)(bA + (m + 4) * 2048 + kh * 1024 + fr * 64 + cA);

    // q3: (afH, bf1) ; q4: (afH, bf0)
    PRIO1();
#pragma unroll
    for (int m = 0; m < 4; ++m)
#pragma unroll
      for (int n = 0; n < 2; ++n)
#pragma unroll
        for (int kh = 0; kh < 2; ++kh)
          acc[m + 4][n + 2] = __builtin_amdgcn_mfma_f32_16x16x32_bf16(afH[m][kh], bf1[n][kh], acc[m + 4][n + 2], 0, 0, 0);
#pragma unroll
    for (int m = 0; m < 4; ++m)
#pragma unroll
      for (int n = 0; n < 2; ++n)
#pragma unroll
        for (int kh = 0; kh < 2; ++kh)
          acc[m + 4][n] = __builtin_amdgcn_mfma_f32_16x16x32_bf16(afH[m][kh], bf0[n][kh], acc[m + 4][n], 0, 0, 0);
    PRIO0();

    // BAR#1: every wave's kbuf-c reads are drained (q3/q4 operand deps) -> free
    BAR();

    // stage kbuf c <- K-tile t+2 (clamped tail keeps vmcnt uniform)
    const int ktn = (t + 2 < 64) ? t + 2 : 63;
    stage(Abase, &sA[c][0][0], 0, ktn);
    stage(Abase, &sA[c][1][0], 1, ktn);
    stage(Bbase, &sB[c][0][0], 0, ktn);
    stage(Bbase, &sB[c][1][0], 1, ktn);

    // VM8: t+1's 8 loads landed (t+2's 8 outstanding); BAR#2: visible to all
    VM8();
    BAR();

    // issue next tile's reads from kbuf c^1; service overlaps q3/q4 in pipe
#pragma unroll
    for (int m = 0; m < 4; ++m)
#pragma unroll
      for (int kh = 0; kh < 2; ++kh)
        afL[m][kh] = *(const short8*)(bAn + m * 2048 + kh * 1024 + fr * 64 + cA);
#pragma unroll
    for (int n = 0; n < 2; ++n)
#pragma unroll
      for (int kh = 0; kh < 2; ++kh) {
        bf0[n][kh] = *(const short8*)(bBn + (nsub + n) * 2048 + kh * 1024 + fr * 64 + cA);
        bf1[n][kh] = *(const short8*)(bBn + (nsub + n + 2) * 2048 + kh * 1024 + fr * 64 + cA);
      }
  }

  // epilogue: verified C/D mapping: row = m*16 + fk*4 + j, col = n*16 + fr
  const int rbase = brow * 256 + wm * 128;
  const int cbase = bcol * 256 + wn * 64;
#pragma unroll
  for (int m = 0; m < 8; ++m)
#pragma unroll
    for (int n = 0; n < 4; ++n)
#pragma unroll
      for (int j = 0; j < 4; ++j) {
        int rr = rbase + m * 16 + fk * 4 + j;
        int cc = cbase + n * 16 + fr;
        C[(size_t)rr * GK + cc] = acc[m][n][j];
      }
}

// ---------------------------------------------------------------------------
extern "C" void kernel_launch(void* const* d_in, const int* in_sizes, int n_in,
                              void* d_out, int out_size, void* d_ws, size_t ws_size,
                              hipStream_t stream) {
  const float* x = (const float*)d_in[0];
  const float* W = (const float*)d_in[1];
  const float* lut = (const float*)d_in[2];
  float* out = (float*)d_out;

  unsigned short* xb = (unsigned short*)d_ws;                  // 32 MB bf16 x
  unsigned short* qb = xb + (size_t)4096 * 4096;               // 32 MB bf16 qweight

  prep_kernel<<<8192, 256, 0, stream>>>(x, W, lut, xb, qb);
  gemm_bt<<<256, 512, 0, stream>>>(xb, qb, out);
}